// Round 14
// baseline (418.782 us; speedup 1.0000x reference)
//
#include <hip/hip_runtime.h>
#include <hip/hip_bf16.h>

#define LN_EPS 1e-5f

typedef __attribute__((ext_vector_type(8))) short short8;   // 8 bf16
typedef __attribute__((ext_vector_type(4))) float f32x4;    // MFMA C/D frag

__device__ __forceinline__ ushort f2bf(float f) {
    __hip_bfloat16 h = __float2bfloat16(f);
    return *reinterpret_cast<ushort*>(&h);
}
__device__ __forceinline__ float bf2f(ushort u) {
    union { float f; unsigned int i; } c; c.i = ((unsigned int)u) << 16; return c.f;
}

// ---------------- kprep: weight prep (blk 0-335) + LN0 pass 1 (blk 336-2383) ---------
__global__ void kprep(const float* __restrict__ qW, const float* __restrict__ kW,
                      const float* __restrict__ m1W, const float* __restrict__ m2W,
                      const float* __restrict__ vW,
                      ushort* __restrict__ qWc, ushort* __restrict__ kWT,
                      ushort* __restrict__ m1Wc, ushort* __restrict__ m2Wc,
                      ushort* __restrict__ vWc,
                      const float* __restrict__ inp, float* __restrict__ sums) {
    __shared__ float tile[64][65];
    __shared__ float r1[256], r2[256];
    int blk = blockIdx.x, t = threadIdx.x;
    if (blk < 288) {   // straight 64x64-tile casts
        int col = t & 63, rq = t >> 6;
        const float* src; ushort* dst; int C, tr, tc;
        if (blk < 48)        { int it = blk >> 4, rem = blk & 15; C = 256; tr = rem >> 2; tc = rem & 3;
                               src = qW + it * 65536;  dst = qWc + it * 65536; }
        else if (blk < 96)   { int li = blk - 48; int it = li >> 4, rem = li & 15; C = 256; tr = rem >> 2; tc = rem & 3;
                               src = vW + it * 65536;  dst = vWc + it * 65536; }
        else if (blk < 192)  { int li = blk - 96; int it = li >> 5, rem = li & 31; C = 256; tr = rem >> 2; tc = rem & 3;
                               src = m1W + it * 131072; dst = m1Wc + it * 131072; }
        else                 { int li = blk - 192; int it = li >> 5, rem = li & 31; C = 512; tr = rem >> 3; tc = rem & 7;
                               src = m2W + it * 131072; dst = m2Wc + it * 131072; }
        #pragma unroll
        for (int r = 0; r < 16; r++) {
            int row = r * 4 + rq;
            int idx = (tr * 64 + row) * C + tc * 64 + col;
            dst[idx] = f2bf(src[idx]);
        }
        return;
    }
    if (blk < 336) {   // kWT transpose
        int col = t & 63, rq = t >> 6;
        int li = blk - 288; int it = li >> 4, rem = li & 15;
        int tr = rem >> 2, tc = rem & 3;
        const float* src = kW + it * 65536; ushort* dst = kWT + it * 65536;
        #pragma unroll
        for (int r = 0; r < 16; r++) {
            int row = r * 4 + rq;
            tile[row][col] = src[(tr * 64 + row) * 256 + tc * 64 + col];
        }
        __syncthreads();
        #pragma unroll
        for (int r = 0; r < 16; r++) {
            int row = r * 4 + rq;
            dst[(tc * 64 + row) * 256 + tr * 64 + col] = f2bf(tile[col][row]);
        }
        return;
    }
    // ---- LN0 pass 1 ----
    int lb = blk - 336;
    int b = lb >> 5, seg = lb & 31;
    const float4* p = (const float4*)inp + (size_t)b * 262144 + seg * 8192 + t;
    float s = 0.f, sq = 0.f;
    #pragma unroll
    for (int k = 0; k < 32; k++) {
        float4 v = p[k * 256];
        s  += v.x + v.y + v.z + v.w;
        sq += v.x * v.x + v.y * v.y + v.z * v.z + v.w * v.w;
    }
    r1[t] = s; r2[t] = sq; __syncthreads();
    for (int st = 128; st > 0; st >>= 1) {
        if (t < st) { r1[t] += r1[t + st]; r2[t] += r2[t + st]; }
        __syncthreads();
    }
    if (t == 0) { atomicAdd(&sums[b], r1[0]); atomicAdd(&sums[64 + b], r2[0]); }
}

// ---------------- q-gen core (1024-thread variant) -----------------------------------
__device__ __forceinline__ void qgen_core(
        int b, int t, int lane, int w, int l15, int quad,
        ushort* slbq, float* qsf, ushort* qsb, ushort* qkl,
        const ushort* __restrict__ qWc, const float* __restrict__ qb,
        const ushort* __restrict__ kWT, const float* __restrict__ kb,
        ushort* __restrict__ qkf, float* __restrict__ qkb,
        float* __restrict__ denom_out) {
    {
        short8 aq[8];
        #pragma unroll
        for (int ds = 0; ds < 8; ds++)
            aq[ds] = *(const short8*)(&slbq[l15 * 264 + ds * 32 + quad * 8]);
        int et = w;
        f32x4 c = f32x4{0.f, 0.f, 0.f, 0.f};
        #pragma unroll
        for (int ds = 0; ds < 8; ds++) {
            short8 bf_ = *(const short8*)(qWc + (size_t)(et * 16 + l15) * 256 + ds * 32 + quad * 8);
            c = __builtin_amdgcn_mfma_f32_16x16x32_bf16(aq[ds], bf_, c, 0, 0, 0);
        }
        float qbv = qb[et * 16 + l15];
        #pragma unroll
        for (int r = 0; r < 4; r++) {
            float val = (c[r] + qbv) * (1.f / 16.f);
            qsf[(quad * 4 + r) * 260 + et * 16 + l15] = val;
            qsb[(quad * 4 + r) * 264 + et * 16 + l15] = f2bf(val);
        }
    }
    __syncthreads();
    {
        float pp = 0.f;
        #pragma unroll
        for (int e = 0; e < 16; e++) pp += qsf[w * 260 + l15 * 16 + e] * kb[l15 * 16 + e];
        pp += __shfl_xor(pp, 1); pp += __shfl_xor(pp, 2);
        pp += __shfl_xor(pp, 4); pp += __shfl_xor(pp, 8);
        if (lane == 0) qkb[b * 16 + w] = pp;
    }
    if (t < 16) denom_out[b * 16 + t] = 0.f;
    {
        short8 aq2[8];
        #pragma unroll
        for (int es = 0; es < 8; es++)
            aq2[es] = *(const short8*)(&qsb[l15 * 264 + es * 32 + quad * 8]);
        int dt = w;
        f32x4 c2 = f32x4{0.f, 0.f, 0.f, 0.f};
        #pragma unroll
        for (int es = 0; es < 8; es++) {
            short8 bf2 = *(const short8*)(kWT + (size_t)(dt * 16 + l15) * 256 + es * 32 + quad * 8);
            c2 = __builtin_amdgcn_mfma_f32_16x16x32_bf16(aq2[es], bf2, c2, 0, 0, 0);
        }
        #pragma unroll
        for (int r = 0; r < 4; r++)
            qkl[(quad * 4 + r) * 264 + dt * 16 + l15] = f2bf(c2[r]);
    }
    __syncthreads();
    if (w < 8) {
        short8 v = *(const short8*)(&qkl[l15 * 264 + w * 32 + quad * 8]);
        *(short8*)(qkf + (size_t)(b * 8 + w) * 512 + lane * 8) = v;
    }
}

// ---------------- lkq: LN0 pass 2 (blk 0-255) + initial q-gen (blk 256-319) ----------
__global__ void lkq(const float* __restrict__ inp, const float* __restrict__ ln0w,
                    const float* __restrict__ ln0b, const float* __restrict__ sums,
                    ushort* __restrict__ xgs,
                    const float* __restrict__ slots_init, const float* __restrict__ mu,
                    const float* __restrict__ logsig,
                    const float* __restrict__ ln1w, const float* __restrict__ ln1b,
                    const ushort* __restrict__ qWc, const float* __restrict__ qb,
                    const ushort* __restrict__ kWT, const float* __restrict__ kb,
                    ushort* __restrict__ qkf, float* __restrict__ qkb,
                    float* __restrict__ denom) {
    __shared__ ushort slbq[16 * 264];
    __shared__ ushort qsb[16 * 264];
    __shared__ ushort qkl[16 * 264];
    __shared__ float  qsf[16 * 260];
    __shared__ float  wr1[16], wr2[16];
    int t = threadIdx.x;
    int lane = t & 63, w = t >> 6, l15 = lane & 15, quad = lane >> 4;

    if (blockIdx.x < 256) {
        int gw = blockIdx.x * 16 + w;                 // 4096 wave tasks
        int ntile = gw >> 4;
        int ds = (gw >> 1) & 7;
        int b0 = (gw & 1) * 32;
        int n = ntile * 16 + l15;
        int dcol = ds * 32 + quad * 8;
        const float4* wp = (const float4*)(ln0w + n * 256 + dcol);
        const float4* bp = (const float4*)(ln0b + n * 256 + dcol);
        float4 w0 = wp[0], w1 = wp[1];
        float4 c0 = bp[0], c1 = bp[1];
        #pragma unroll 4
        for (int bi = 0; bi < 32; bi++) {
            int b = b0 + (31 - bi);                   // reversed: L3-resident tail first
            float mean = sums[b] * (1.f / 1048576.f);
            float rstd = rsqrtf(sums[64 + b] * (1.f / 1048576.f) - mean * mean + LN_EPS);
            const float4* xp = (const float4*)(inp + (size_t)b * 1048576 + n * 256 + dcol);
            float4 v0 = xp[0], v1 = xp[1];
            ushort o[8];
            o[0] = f2bf((v0.x - mean) * rstd * w0.x + c0.x);
            o[1] = f2bf((v0.y - mean) * rstd * w0.y + c0.y);
            o[2] = f2bf((v0.z - mean) * rstd * w0.z + c0.z);
            o[3] = f2bf((v0.w - mean) * rstd * w0.w + c0.w);
            o[4] = f2bf((v1.x - mean) * rstd * w1.x + c1.x);
            o[5] = f2bf((v1.y - mean) * rstd * w1.y + c1.y);
            o[6] = f2bf((v1.z - mean) * rstd * w1.z + c1.z);
            o[7] = f2bf((v1.w - mean) * rstd * w1.w + c1.w);
            *(short8*)(xgs + ((size_t)((b * 256 + ntile) * 8 + ds) * 64 + lane) * 8) = *(short8*)o;
        }
        return;
    }
    int b = blockIdx.x - 256;
    int g = t >> 8, c = t & 255;
    float muv = mu[c];
    float sgv = __expf(logsig[c]);
    float vals[4]; float s = 0.f, sq = 0.f;
    #pragma unroll
    for (int kk = 0; kk < 4; kk++) {
        float v = muv + sgv * slots_init[b * 4096 + (g * 4 + kk) * 256 + c];
        vals[kk] = v; s += v; sq += v * v;
    }
    #pragma unroll
    for (int m = 1; m < 64; m <<= 1) { s += __shfl_xor(s, m); sq += __shfl_xor(sq, m); }
    if (lane == 0) { wr1[w] = s; wr2[w] = sq; }
    __syncthreads();
    float ts = 0.f, tsq = 0.f;
    #pragma unroll
    for (int i = 0; i < 16; i++) { ts += wr1[i]; tsq += wr2[i]; }
    float m_  = ts * (1.f / 4096.f);
    float rs_ = rsqrtf(tsq * (1.f / 4096.f) - m_ * m_ + LN_EPS);
    #pragma unroll
    for (int kk = 0; kk < 4; kk++) {
        int k = g * 4 + kk;
        slbq[k * 264 + c] = f2bf((vals[kk] - m_) * rs_ * ln1w[k * 256 + c] + ln1b[k * 256 + c]);
    }
    __syncthreads();
    qgen_core(b, t, lane, w, l15, quad, slbq, qsf, qsb, qkl,
              qWc, qb, kWT, kb, qkf, qkb, denom);
}

// ---------------- THE hot kernel: ns/dtile-split ax -> 18.6 KB LDS, 6 blocks/CU ------
// Wave w owns d-tiles {w, w+4, w+8, w+12}. Per sub: dist -> softmax -> transpose A
// (ds 0-3 -> dtiles 0-7) -> barrier -> ax A (dtiles w,w+4) -> barrier -> transpose B
// (ds 4-7 -> dtiles 8-15) -> prefetch -> barrier -> ax B (dtiles w+8,w+12).
__launch_bounds__(256, 6)
__global__ void katt(const ushort* __restrict__ xgs, const ushort* __restrict__ qkf,
                     const float* __restrict__ qkb, float* __restrict__ denom,
                     ushort* __restrict__ partials) {
    int b = blockIdx.x >> 4, chunk = blockIdx.x & 15;
    int tid = threadIdx.x;
    int lane = tid & 63, w = tid >> 6;
    int l15 = lane & 15, quad = lane >> 4;

    __shared__ ushort xtT[8192];        // 8 dtile-frags x (ns,512) = 16 KB (half tile)
    __shared__ ushort attn[16 * 72];    // attn [s][n_local], pitch 72

    short8 ilo, ihi;
    #pragma unroll
    for (int j = 0; j < 8; j++) {
        ilo[j] = (short)((quad * 8 + j == l15)      ? 0x3F80 : 0);
        ihi[j] = (short)((quad * 8 + j == l15 + 16) ? 0x3F80 : 0);
    }
    // writer base inside a (dtile,ns) frag-pair region: (ns=w>>1)*512 + perm + elem
    int wbase = (w >> 1) * 512 + ((w * 2 + (quad >> 1)) & 3) * 128 + l15 * 8 + (quad & 1) * 4;

    short8 qkfr[8];
    #pragma unroll
    for (int ds = 0; ds < 8; ds++)
        qkfr[ds] = *(const short8*)(qkf + ((size_t)(b * 8 + ds) * 512 + lane * 8));
    float4 qo = *(const float4*)(qkb + b * 16 + quad * 4);

    f32x4 pacc[4];      // pacc[u] accumulates dtile = w + u*4
    #pragma unroll
    for (int u = 0; u < 4; u++) pacc[u] = f32x4{0.f, 0.f, 0.f, 0.f};
    float dp0 = 0.f, dp1 = 0.f, dp2 = 0.f, dp3 = 0.f;

    int tile0 = b * 256 + chunk * 16;

    short8 pf[8];
    #pragma unroll
    for (int i = 0; i < 8; i++)
        pf[i] = *(const short8*)(xgs + (((size_t)(tile0 + w) * 8 + i) * 64 + lane) * 8);

    #pragma unroll 1
    for (int sub = 0; sub < 4; sub++) {
        __syncthreads();                // prev ax B done reading xtT/attn
        // ===== dist from pf =====
        f32x4 dc = f32x4{0.f, 0.f, 0.f, 0.f};
        #pragma unroll
        for (int ds = 0; ds < 8; ds++)
            dc = __builtin_amdgcn_mfma_f32_16x16x32_bf16(qkfr[ds], pf[ds], dc, 0, 0, 0);
        dc[0] += qo.x; dc[1] += qo.y; dc[2] += qo.z; dc[3] += qo.w;
        float mx = fmaxf(fmaxf(dc[0], dc[1]), fmaxf(dc[2], dc[3]));
        mx = fmaxf(mx, __shfl_xor(mx, 16));
        mx = fmaxf(mx, __shfl_xor(mx, 32));
        float e0 = __expf(dc[0] - mx), e1 = __expf(dc[1] - mx);
        float e2 = __expf(dc[2] - mx), e3 = __expf(dc[3] - mx);
        float lsum = e0 + e1 + e2 + e3;
        lsum += __shfl_xor(lsum, 16); lsum += __shfl_xor(lsum, 32);
        float inv = 1.f / lsum;
        float p0 = e0 * inv, p1 = e1 * inv, p2 = e2 * inv, p3 = e3 * inv;
        dp0 += p0; dp1 += p1; dp2 += p2; dp3 += p3;
        attn[(quad * 4 + 0) * 72 + w * 16 + l15] = f2bf(p0);
        attn[(quad * 4 + 1) * 72 + w * 16 + l15] = f2bf(p1);
        attn[(quad * 4 + 2) * 72 + w * 16 + l15] = f2bf(p2);
        attn[(quad * 4 + 3) * 72 + w * 16 + l15] = f2bf(p3);
        f32x4 zz = f32x4{0.f, 0.f, 0.f, 0.f};
        // ===== transpose A: ds 0-3 -> dtiles 0-7 =====
        #pragma unroll
        for (int ds = 0; ds < 4; ds++) {
            f32x4 tlo = __builtin_amdgcn_mfma_f32_16x16x32_bf16(pf[ds], ilo, zz, 0, 0, 0);
            f32x4 thi = __builtin_amdgcn_mfma_f32_16x16x32_bf16(pf[ds], ihi, zz, 0, 0, 0);
            unsigned lo0 = (__float_as_uint(tlo[0]) >> 16) | (__float_as_uint(tlo[1]) & 0xFFFF0000u);
            unsigned lo1 = (__float_as_uint(tlo[2]) >> 16) | (__float_as_uint(tlo[3]) & 0xFFFF0000u);
            unsigned hi0 = (__float_as_uint(thi[0]) >> 16) | (__float_as_uint(thi[1]) & 0xFFFF0000u);
            unsigned hi1 = (__float_as_uint(thi[2]) >> 16) | (__float_as_uint(thi[3]) & 0xFFFF0000u);
            *(uint2*)(&xtT[(ds * 2 + 0) * 1024 + wbase]) = make_uint2(lo0, lo1);   // dtile 2ds
            *(uint2*)(&xtT[(ds * 2 + 1) * 1024 + wbase]) = make_uint2(hi0, hi1);   // dtile 2ds+1
        }
        __syncthreads();                // xtT A visible
        // ===== ax A: dtiles w (u=0), w+4 (u=1) =====
        #pragma unroll
        for (int ns = 0; ns < 2; ns++) {
            short8 aa = *(const short8*)(&attn[l15 * 72 + ns * 32 + quad * 8]);
            #pragma unroll
            for (int u = 0; u < 2; u++) {
                int dtile = w + u * 4;                 // 0..7
                short8 bb = *(const short8*)(&xtT[(dtile * 2 + ns) * 512 + lane * 8]);
                pacc[u] = __builtin_amdgcn_mfma_f32_16x16x32_bf16(aa, bb, pacc[u], 0, 0, 0);
            }
        }
        __syncthreads();                // ax A done; xtT reusable
        // ===== transpose B: ds 4-7 -> dtiles 8-15 (stored at frag dtile-8) =====
        #pragma unroll
        for (int ds = 4; ds < 8; ds++) {
            f32x4 tlo = __builtin_amdgcn_mfma_f32_16x16x32_bf16(pf[ds], ilo, zz, 0, 0, 0);
            f32x4 thi = __builtin_amdgcn_mfma_f32_16x16x32_bf16(pf[ds], ihi, zz, 0, 0, 0);
            unsigned lo0 = (__float_as_uint(tlo[0]) >> 16) | (__float_as_uint(tlo[1]) & 0xFFFF0000u);
            unsigned lo1 = (__float_as_uint(tlo[2]) >> 16) | (__float_as_uint(tlo[3]) & 0xFFFF0000u);
            unsigned hi0 = (__float_as_uint(thi[0]) >> 16) | (__float_as_uint(thi[1]) & 0xFFFF0000u);
            unsigned hi1 = (__float_as_uint(thi[2]) >> 16) | (__float_as_uint(thi[3]) & 0xFFFF0000u);
            *(uint2*)(&xtT[((ds - 4) * 2 + 0) * 1024 + wbase]) = make_uint2(lo0, lo1); // dtile 2ds
            *(uint2*)(&xtT[((ds - 4) * 2 + 1) * 1024 + wbase]) = make_uint2(hi0, hi1); // dtile 2ds+1
        }
        if (sub < 3) {                  // pf fully consumed -> prefetch next sub
            #pragma unroll
            for (int i = 0; i < 8; i++)
                pf[i] = *(const short8*)(xgs + (((size_t)(tile0 + (sub + 1) * 4 + w) * 8 + i) * 64 + lane) * 8);
        }
        __syncthreads();                // xtT B visible
        // ===== ax B: dtiles w+8 (u=2), w+12 (u=3) =====
        #pragma unroll
        for (int ns = 0; ns < 2; ns++) {
            short8 aa = *(const short8*)(&attn[l15 * 72 + ns * 32 + quad * 8]);
            #pragma unroll
            for (int u = 2; u < 4; u++) {
                int dtile = w + u * 4;                 // 8..15; frag at dtile-8
                short8 bb = *(const short8*)(&xtT[((dtile - 8) * 2 + ns) * 512 + lane * 8]);
                pacc[u] = __builtin_amdgcn_mfma_f32_16x16x32_bf16(aa, bb, pacc[u], 0, 0, 0);
            }
        }
    }

    #pragma unroll
    for (int m = 1; m < 16; m <<= 1) {
        dp0 += __shfl_xor(dp0, m); dp1 += __shfl_xor(dp1, m);
        dp2 += __shfl_xor(dp2, m); dp3 += __shfl_xor(dp3, m);
    }
    if (l15 == 0) {
        atomicAdd(&denom[b * 16 + quad * 4 + 0], dp0);
        atomicAdd(&denom[b * 16 + quad * 4 + 1], dp1);
        atomicAdd(&denom[b * 16 + quad * 4 + 2], dp2);
        atomicAdd(&denom[b * 16 + quad * 4 + 3], dp3);
    }

    ushort* pout = partials + (size_t)(b * 16 + chunk) * 4096;   // [s][d] bf16
    #pragma unroll
    for (int u = 0; u < 4; u++)
        #pragma unroll
        for (int r = 0; r < 4; r++)
            pout[(quad * 4 + r) * 256 + (w + u * 4) * 16 + l15] = f2bf(pacc[u][r]);
}

// ---------------- fused tail, 1024 threads; partials read as bf16 --------------------
__global__ void ktail(const ushort* __restrict__ partials, const float* __restrict__ denom,
                      const ushort* __restrict__ vWc, const float* __restrict__ vb,
                      const float* __restrict__ ln2w, const float* __restrict__ ln2b,
                      const ushort* __restrict__ m1Wc, const float* __restrict__ m1b,
                      const ushort* __restrict__ m2Wc, const float* __restrict__ m2b,
                      float* __restrict__ final_out, int write_final,
                      const float* __restrict__ ln1w, const float* __restrict__ ln1b,
                      const ushort* __restrict__ qWc_n, const float* __restrict__ qb_n,
                      const ushort* __restrict__ kWT_n, const float* __restrict__ kb_n,
                      ushort* __restrict__ qkf, float* __restrict__ qkb,
                      float* __restrict__ denom_out, int gen) {
    int b = blockIdx.x, t = threadIdx.x;
    int lane = t & 63, w = t >> 6, l15 = lane & 15, quad = lane >> 4;

    __shared__ char pool[60416];
    __shared__ float dnb[16];
    __shared__ float wr1[16], wr2[16];
    ushort* axsb = (ushort*)pool;                  // [0,8448)
    ushort* s2b  = (ushort*)(pool + 8448);         // [8448,16896)
    float*  slt  = (float*)(pool + 16896);         // [16896,33280)
    ushort* hlb  = (ushort*)(pool + 35328);        // [35328,51968)
    float*  slt2 = (float*)pool;                   // P6 [0,16384)
    ushort* slbq = (ushort*)(pool + 16896);        // P6
    ushort* qkl  = (ushort*)(pool + 16896);        // P6 (after slbq A-frags loaded)
    float*  qsf  = (float*)(pool + 35328);         // P6
    ushort* qsb  = (ushort*)(pool + 51968);        // P6

    // ---- P1: reduce partials chunks (bf16) -> axsb ----
    const ushort* pp = partials + (size_t)b * 65536;
    #pragma unroll
    for (int i = 0; i < 4; i++) {
        int idx = i * 1024 + t;
        float ss = 0.f;
        #pragma unroll
        for (int c = 0; c < 16; c++) ss += bf2f(pp[c * 4096 + idx]);
        axsb[(idx >> 8) * 264 + (idx & 255)] = f2bf(ss);
    }
    if (t < 16) dnb[t] = denom[b * 16 + t];
    __syncthreads();

    // ---- P2: v-apply (MFMA); wave w -> e-tile w ----
    float myv[4];
    {
        short8 af[8];
        #pragma unroll
        for (int ds = 0; ds < 8; ds++)
            af[ds] = *(const short8*)(&axsb[l15 * 264 + ds * 32 + quad * 8]);
        int et = w;
        f32x4 c = f32x4{0.f, 0.f, 0.f, 0.f};
        #pragma unroll
        for (int ds = 0; ds < 8; ds++) {
            short8 bf_ = *(const short8*)(vWc + (size_t)(et * 16 + l15) * 256 + ds * 32 + quad * 8);
            c = __builtin_amdgcn_mfma_f32_16x16x32_bf16(af[ds], bf_, c, 0, 0, 0);
        }
        float vbe = vb[et * 16 + l15];
        #pragma unroll
        for (int r = 0; r < 4; r++) {
            float A = dnb[quad * 4 + r];
            float val = (c[r] + vbe * A) / (A + 1e-7f);
            slt[(quad * 4 + r) * 256 + et * 16 + l15] = val;
            myv[r] = val;
        }
    }
    {
        float s = myv[0] + myv[1] + myv[2] + myv[3];
        float sq = myv[0]*myv[0] + myv[1]*myv[1] + myv[2]*myv[2] + myv[3]*myv[3];
        #pragma unroll
        for (int m = 1; m < 64; m <<= 1) { s += __shfl_xor(s, m); sq += __shfl_xor(sq, m); }
        if (lane == 0) { wr1[w] = s; wr2[w] = sq; }
        __syncthreads();
    }
    float ts = 0.f, tsq = 0.f;
    #pragma unroll
    for (int i = 0; i < 16; i++) { ts += wr1[i]; tsq += wr2[i]; }
    float m2_ = ts * (1.f / 4096.f);
    float rs2 = rsqrtf(tsq * (1.f / 4096.f) - m2_ * m2_ + LN_EPS);
    {
        int e = w * 16 + l15;
        #pragma unroll
        for (int r = 0; r < 4; r++) {
            int ss_ = quad * 4 + r;
            s2b[ss_ * 264 + e] = f2bf((myv[r] - m2_) * rs2 * ln2w[ss_ * 256 + e] + ln2b[ss_ * 256 + e]);
        }
    }
    __syncthreads();

    // ---- P4: MLP1 (MFMA); wave w -> j-tiles {w, w+16} ----
    {
        short8 a2[8];
        #pragma unroll
        for (int ds = 0; ds < 8; ds++)
            a2[ds] = *(const short8*)(&s2b[l15 * 264 + ds * 32 + quad * 8]);
        #pragma unroll
        for (int p = 0; p < 2; p++) {
            int jt = w + p * 16;
            f32x4 c = f32x4{0.f, 0.f, 0.f, 0.f};
            #pragma unroll
            for (int ds = 0; ds < 8; ds++) {
                short8 bf_ = *(const short8*)(m1Wc + (size_t)(jt * 16 + l15) * 256 + ds * 32 + quad * 8);
                c = __builtin_amdgcn_mfma_f32_16x16x32_bf16(a2[ds], bf_, c, 0, 0, 0);
            }
            float bias = m1b[jt * 16 + l15];
            #pragma unroll
            for (int r = 0; r < 4; r++)
                hlb[(quad * 4 + r) * 520 + jt * 16 + l15] = f2bf(fmaxf(c[r] + bias, 0.f));
        }
    }
    __syncthreads();

    // ---- P5: MLP2 (MFMA) + residual; wave w -> d-tile w ----
    {
        short8 a3[16];
        #pragma unroll
        for (int js = 0; js < 16; js++)
            a3[js] = *(const short8*)(&hlb[l15 * 520 + js * 32 + quad * 8]);
        int dt = w;
        f32x4 c = f32x4{0.f, 0.f, 0.f, 0.f};
        #pragma unroll
        for (int js = 0; js < 16; js++) {
            short8 bf_ = *(const short8*)(m2Wc + (size_t)(dt * 16 + l15) * 512 + js * 32 + quad * 8);
            c = __builtin_amdgcn_mfma_f32_16x16x32_bf16(a3[js], bf_, c, 0, 0, 0);
        }
        float b2 = m2b[dt * 16 + l15];
        #pragma unroll
        for (int r = 0; r < 4; r++) {
            int ss_ = quad * 4 + r, d = dt * 16 + l15;
            float val = slt[ss_ * 256 + d] + c[r] + b2;
            slt2[ss_ * 256 + d] = val;
            if (write_final) final_out[(size_t)b * 4096 + ss_ * 256 + d] = val;
        }
    }
    __syncthreads();

    // ---- P6: next-iter q-gen (slots from LDS) ----
    if (gen) {
        int g = t >> 8, cc = t & 255;
        float vals[4]; float s = 0.f, sq = 0.f;
        #pragma unroll
        for (int kk = 0; kk < 4; kk++) {
            float v = slt2[(g * 4 + kk) * 256 + cc];
            vals[kk] = v; s += v; sq += v * v;
        }
        #pragma unroll
        for (int m = 1; m < 64; m <<= 1) { s += __shfl_xor(s, m); sq += __shfl_xor(sq, m); }
        if (lane == 0) { wr1[w] = s; wr2[w] = sq; }
        __syncthreads();
        float ts1 = 0.f, tsq1 = 0.f;
        #pragma unroll
        for (int i = 0; i < 16; i++) { ts1 += wr1[i]; tsq1 += wr2[i]; }
        float m1_ = ts1 * (1.f / 4096.f);
        float rs1 = rsqrtf(tsq1 * (1.f / 4096.f) - m1_ * m1_ + LN_EPS);
        #pragma unroll
        for (int kk = 0; kk < 4; kk++) {
            int k = g * 4 + kk;
            slbq[k * 264 + cc] = f2bf((vals[kk] - m1_) * rs1 * ln1w[k * 256 + cc] + ln1b[k * 256 + cc]);
        }
        __syncthreads();
        qgen_core(b, t, lane, w, l15, quad, slbq, qsf, qsb, qkl,
                  qWc_n, qb_n, kWT_n, kb_n, qkf, qkb, denom_out);
    }
}

extern "C" void kernel_launch(void* const* d_in, const int* in_sizes, int n_in,
                              void* d_out, int out_size, void* d_ws, size_t ws_size,
                              hipStream_t stream) {
    const float* inputs     = (const float*)d_in[0];
    const float* slots_init = (const float*)d_in[1];
    const float* mu         = (const float*)d_in[2];
    const float* logsig     = (const float*)d_in[3];
    const float* ln0w       = (const float*)d_in[4];
    const float* ln0b       = (const float*)d_in[5];
    const float* ln1w       = (const float*)d_in[6];
    const float* ln1b       = (const float*)d_in[7];
    const float* ln2w       = (const float*)d_in[8];
    const float* ln2b       = (const float*)d_in[9];
    const float* qW         = (const float*)d_in[10];
    const float* qb         = (const float*)d_in[11];
    const float* kW         = (const float*)d_in[12];
    const float* kb         = (const float*)d_in[13];
    const float* vW         = (const float*)d_in[14];
    const float* vb         = (const float*)d_in[15];
    const float* m1W        = (const float*)d_in[16];
    const float* m1b        = (const float*)d_in[17];
    const float* m2W        = (const float*)d_in[18];
    const float* m2b        = (const float*)d_in[19];

    char* ws = (char*)d_ws;
    ushort* xgs     = (ushort*)(ws);                   // 134,217,728 B
    ushort* partials= (ushort*)(ws + 134217728);       //   8,388,608 B (bf16)
    ushort* qkf     = (ushort*)(ws + 150994944);       //     524,288 B
    ushort* qWc     = (ushort*)(ws + 153616384);       //     393,216 B
    ushort* m1Wc    = (ushort*)(ws + 154009600);       //     786,432 B
    ushort* m2Wc    = (ushort*)(ws + 154796032);       //     786,432 B
    ushort* vWc     = (ushort*)(ws + 155582464);       //     393,216 B
    float*  denom   = (float*)(ws + 155975680);        //       4,096 B
    float*  qkb     = (float*)(ws + 155979776);        //       4,096 B
    float*  sums    = (float*)(ws + 155983872);        //         512 B
    ushort* kWT     = (ushort*)(ws + 155984384);       //     393,216 B
    // total 156,377,600 B <= 157,295,104 B proven available

    hipMemsetAsync(sums, 0, 512, stream);
    kprep<<<2384, 256, 0, stream>>>(qW, kW, m1W, m2W, vW, qWc, kWT, m1Wc, m2Wc, vWc,
                                    inputs, sums);
    lkq<<<320, 1024, 0, stream>>>(inputs, ln0w, ln0b, sums, xgs,
                                  slots_init, mu, logsig, ln1w, ln1b,
                                  qWc, qb, kWT, kb, qkf, qkb, denom);

    for (int it = 0; it < 3; it++) {
        katt<<<1024, 256, 0, stream>>>(xgs, qkf, qkb, denom, partials);
        int nx = (it < 2) ? it + 1 : 2;
        ktail<<<64, 1024, 0, stream>>>(partials, denom,
                                       vWc + it * 65536, vb + it * 256, ln2w, ln2b,
                                       m1Wc + it * 131072, m1b + it * 512,
                                       m2Wc + it * 131072, m2b + it * 256,
                                       (float*)d_out, it == 2 ? 1 : 0,
                                       ln1w, ln1b,
                                       qWc + nx * 65536, qb + nx * 256,
                                       kWT + nx * 65536, kb + nx * 256,
                                       qkf, qkb, denom, it < 2 ? 1 : 0);
    }
}

// Round 15
// 310.779 us; speedup vs baseline: 1.3475x; 1.3475x over previous
//
#include <hip/hip_runtime.h>
#include <hip/hip_bf16.h>

#define LN_EPS 1e-5f

typedef __attribute__((ext_vector_type(8))) short short8;   // 8 bf16
typedef __attribute__((ext_vector_type(4))) float f32x4;    // MFMA C/D frag

__device__ __forceinline__ ushort f2bf(float f) {
    __hip_bfloat16 h = __float2bfloat16(f);
    return *reinterpret_cast<ushort*>(&h);
}
__device__ __forceinline__ float bf2f(ushort u) {
    union { float f; unsigned int i; } c; c.i = ((unsigned int)u) << 16; return c.f;
}

// ---------------- kprep: weight prep (blk 0-335) + LN0 pass 1 (blk 336-2383) ---------
__global__ void kprep(const float* __restrict__ qW, const float* __restrict__ kW,
                      const float* __restrict__ m1W, const float* __restrict__ m2W,
                      const float* __restrict__ vW,
                      ushort* __restrict__ qWc, ushort* __restrict__ kWT,
                      ushort* __restrict__ m1Wc, ushort* __restrict__ m2Wc,
                      ushort* __restrict__ vWc,
                      const float* __restrict__ inp, float* __restrict__ sums) {
    __shared__ float tile[64][65];
    __shared__ float r1[256], r2[256];
    int blk = blockIdx.x, t = threadIdx.x;
    if (blk < 288) {   // straight 64x64-tile casts
        int col = t & 63, rq = t >> 6;
        const float* src; ushort* dst; int C, tr, tc;
        if (blk < 48)        { int it = blk >> 4, rem = blk & 15; C = 256; tr = rem >> 2; tc = rem & 3;
                               src = qW + it * 65536;  dst = qWc + it * 65536; }
        else if (blk < 96)   { int li = blk - 48; int it = li >> 4, rem = li & 15; C = 256; tr = rem >> 2; tc = rem & 3;
                               src = vW + it * 65536;  dst = vWc + it * 65536; }
        else if (blk < 192)  { int li = blk - 96; int it = li >> 5, rem = li & 31; C = 256; tr = rem >> 2; tc = rem & 3;
                               src = m1W + it * 131072; dst = m1Wc + it * 131072; }
        else                 { int li = blk - 192; int it = li >> 5, rem = li & 31; C = 512; tr = rem >> 3; tc = rem & 7;
                               src = m2W + it * 131072; dst = m2Wc + it * 131072; }
        #pragma unroll
        for (int r = 0; r < 16; r++) {
            int row = r * 4 + rq;
            int idx = (tr * 64 + row) * C + tc * 64 + col;
            dst[idx] = f2bf(src[idx]);
        }
        return;
    }
    if (blk < 336) {   // kWT transpose
        int col = t & 63, rq = t >> 6;
        int li = blk - 288; int it = li >> 4, rem = li & 15;
        int tr = rem >> 2, tc = rem & 3;
        const float* src = kW + it * 65536; ushort* dst = kWT + it * 65536;
        #pragma unroll
        for (int r = 0; r < 16; r++) {
            int row = r * 4 + rq;
            tile[row][col] = src[(tr * 64 + row) * 256 + tc * 64 + col];
        }
        __syncthreads();
        #pragma unroll
        for (int r = 0; r < 16; r++) {
            int row = r * 4 + rq;
            dst[(tc * 64 + row) * 256 + tr * 64 + col] = f2bf(tile[col][row]);
        }
        return;
    }
    // ---- LN0 pass 1 ----
    int lb = blk - 336;
    int b = lb >> 5, seg = lb & 31;
    const float4* p = (const float4*)inp + (size_t)b * 262144 + seg * 8192 + t;
    float s = 0.f, sq = 0.f;
    #pragma unroll
    for (int k = 0; k < 32; k++) {
        float4 v = p[k * 256];
        s  += v.x + v.y + v.z + v.w;
        sq += v.x * v.x + v.y * v.y + v.z * v.z + v.w * v.w;
    }
    r1[t] = s; r2[t] = sq; __syncthreads();
    for (int st = 128; st > 0; st >>= 1) {
        if (t < st) { r1[t] += r1[t + st]; r2[t] += r2[t + st]; }
        __syncthreads();
    }
    if (t == 0) { atomicAdd(&sums[b], r1[0]); atomicAdd(&sums[64 + b], r2[0]); }
}

// ---------------- q-gen core (1024-thread variant) -----------------------------------
__device__ __forceinline__ void qgen_core(
        int b, int t, int lane, int w, int l15, int quad,
        ushort* slbq, float* qsf, ushort* qsb, ushort* qkl,
        const ushort* __restrict__ qWc, const float* __restrict__ qb,
        const ushort* __restrict__ kWT, const float* __restrict__ kb,
        ushort* __restrict__ qkf, float* __restrict__ qkb,
        float* __restrict__ denom_out) {
    {
        short8 aq[8];
        #pragma unroll
        for (int ds = 0; ds < 8; ds++)
            aq[ds] = *(const short8*)(&slbq[l15 * 264 + ds * 32 + quad * 8]);
        int et = w;
        f32x4 c = f32x4{0.f, 0.f, 0.f, 0.f};
        #pragma unroll
        for (int ds = 0; ds < 8; ds++) {
            short8 bf_ = *(const short8*)(qWc + (size_t)(et * 16 + l15) * 256 + ds * 32 + quad * 8);
            c = __builtin_amdgcn_mfma_f32_16x16x32_bf16(aq[ds], bf_, c, 0, 0, 0);
        }
        float qbv = qb[et * 16 + l15];
        #pragma unroll
        for (int r = 0; r < 4; r++) {
            float val = (c[r] + qbv) * (1.f / 16.f);
            qsf[(quad * 4 + r) * 260 + et * 16 + l15] = val;
            qsb[(quad * 4 + r) * 264 + et * 16 + l15] = f2bf(val);
        }
    }
    __syncthreads();
    {
        float pp = 0.f;
        #pragma unroll
        for (int e = 0; e < 16; e++) pp += qsf[w * 260 + l15 * 16 + e] * kb[l15 * 16 + e];
        pp += __shfl_xor(pp, 1); pp += __shfl_xor(pp, 2);
        pp += __shfl_xor(pp, 4); pp += __shfl_xor(pp, 8);
        if (lane == 0) qkb[b * 16 + w] = pp;
    }
    if (t < 16) denom_out[b * 16 + t] = 0.f;
    {
        short8 aq2[8];
        #pragma unroll
        for (int es = 0; es < 8; es++)
            aq2[es] = *(const short8*)(&qsb[l15 * 264 + es * 32 + quad * 8]);
        int dt = w;
        f32x4 c2 = f32x4{0.f, 0.f, 0.f, 0.f};
        #pragma unroll
        for (int es = 0; es < 8; es++) {
            short8 bf2 = *(const short8*)(kWT + (size_t)(dt * 16 + l15) * 256 + es * 32 + quad * 8);
            c2 = __builtin_amdgcn_mfma_f32_16x16x32_bf16(aq2[es], bf2, c2, 0, 0, 0);
        }
        #pragma unroll
        for (int r = 0; r < 4; r++)
            qkl[(quad * 4 + r) * 264 + dt * 16 + l15] = f2bf(c2[r]);
    }
    __syncthreads();
    if (w < 8) {
        short8 v = *(const short8*)(&qkl[l15 * 264 + w * 32 + quad * 8]);
        *(short8*)(qkf + (size_t)(b * 8 + w) * 512 + lane * 8) = v;
    }
}

// ---------------- lkq: LN0 pass 2 (blk 0-255) + initial q-gen (blk 256-319) ----------
// Batch loop REVERSED (b=63 first): kprep streamed inputs batch-ascending, so L3
// retains the high-b tail -> reversed re-read turns LRU streaming misses into hits.
__global__ void lkq(const float* __restrict__ inp, const float* __restrict__ ln0w,
                    const float* __restrict__ ln0b, const float* __restrict__ sums,
                    ushort* __restrict__ xgs,
                    const float* __restrict__ slots_init, const float* __restrict__ mu,
                    const float* __restrict__ logsig,
                    const float* __restrict__ ln1w, const float* __restrict__ ln1b,
                    const ushort* __restrict__ qWc, const float* __restrict__ qb,
                    const ushort* __restrict__ kWT, const float* __restrict__ kb,
                    ushort* __restrict__ qkf, float* __restrict__ qkb,
                    float* __restrict__ denom) {
    __shared__ ushort slbq[16 * 264];
    __shared__ ushort qsb[16 * 264];
    __shared__ ushort qkl[16 * 264];
    __shared__ float  qsf[16 * 260];
    __shared__ float  wr1[16], wr2[16];
    int t = threadIdx.x;
    int lane = t & 63, w = t >> 6, l15 = lane & 15, quad = lane >> 4;

    if (blockIdx.x < 256) {
        int gw = blockIdx.x * 16 + w;                 // 4096 wave tasks
        int ntile = gw >> 4;
        int ds = (gw >> 1) & 7;
        int b0 = (gw & 1) * 32;
        int n = ntile * 16 + l15;
        int dcol = ds * 32 + quad * 8;
        const float4* wp = (const float4*)(ln0w + n * 256 + dcol);
        const float4* bp = (const float4*)(ln0b + n * 256 + dcol);
        float4 w0 = wp[0], w1 = wp[1];
        float4 c0 = bp[0], c1 = bp[1];
        #pragma unroll 4
        for (int bi = 0; bi < 32; bi++) {
            int b = b0 + (31 - bi);                   // reversed: L3-resident tail first
            float mean = sums[b] * (1.f / 1048576.f);
            float rstd = rsqrtf(sums[64 + b] * (1.f / 1048576.f) - mean * mean + LN_EPS);
            const float4* xp = (const float4*)(inp + (size_t)b * 1048576 + n * 256 + dcol);
            float4 v0 = xp[0], v1 = xp[1];
            ushort o[8];
            o[0] = f2bf((v0.x - mean) * rstd * w0.x + c0.x);
            o[1] = f2bf((v0.y - mean) * rstd * w0.y + c0.y);
            o[2] = f2bf((v0.z - mean) * rstd * w0.z + c0.z);
            o[3] = f2bf((v0.w - mean) * rstd * w0.w + c0.w);
            o[4] = f2bf((v1.x - mean) * rstd * w1.x + c1.x);
            o[5] = f2bf((v1.y - mean) * rstd * w1.y + c1.y);
            o[6] = f2bf((v1.z - mean) * rstd * w1.z + c1.z);
            o[7] = f2bf((v1.w - mean) * rstd * w1.w + c1.w);
            *(short8*)(xgs + ((size_t)((b * 256 + ntile) * 8 + ds) * 64 + lane) * 8) = *(short8*)o;
        }
        return;
    }
    int b = blockIdx.x - 256;
    int g = t >> 8, c = t & 255;
    float muv = mu[c];
    float sgv = __expf(logsig[c]);
    float vals[4]; float s = 0.f, sq = 0.f;
    #pragma unroll
    for (int kk = 0; kk < 4; kk++) {
        float v = muv + sgv * slots_init[b * 4096 + (g * 4 + kk) * 256 + c];
        vals[kk] = v; s += v; sq += v * v;
    }
    #pragma unroll
    for (int m = 1; m < 64; m <<= 1) { s += __shfl_xor(s, m); sq += __shfl_xor(sq, m); }
    if (lane == 0) { wr1[w] = s; wr2[w] = sq; }
    __syncthreads();
    float ts = 0.f, tsq = 0.f;
    #pragma unroll
    for (int i = 0; i < 16; i++) { ts += wr1[i]; tsq += wr2[i]; }
    float m_  = ts * (1.f / 4096.f);
    float rs_ = rsqrtf(tsq * (1.f / 4096.f) - m_ * m_ + LN_EPS);
    #pragma unroll
    for (int kk = 0; kk < 4; kk++) {
        int k = g * 4 + kk;
        slbq[k * 264 + c] = f2bf((vals[kk] - m_) * rs_ * ln1w[k * 256 + c] + ln1b[k * 256 + c]);
    }
    __syncthreads();
    qgen_core(b, t, lane, w, l15, quad, slbq, qsf, qsb, qkl,
              qWc, qb, kWT, kb, qkf, qkb, denom);
}

// ---------------- THE hot kernel; partials bf16 (R13-proven) -------------------------
__launch_bounds__(256, 4)
__global__ void katt(const ushort* __restrict__ xgs, const ushort* __restrict__ qkf,
                     const float* __restrict__ qkb, float* __restrict__ denom,
                     ushort* __restrict__ partials) {
    int b = blockIdx.x >> 4, chunk = blockIdx.x & 15;
    int tid = threadIdx.x;
    int lane = tid & 63, w = tid >> 6;
    int l15 = lane & 15, quad = lane >> 4;

    __shared__ ushort xtT[16384];       // x^T in ax-B-frag order (32 KB)
    __shared__ ushort attn[16 * 72];    // attn [s][n_local], pitch 72

    short8 ilo, ihi;
    #pragma unroll
    for (int j = 0; j < 8; j++) {
        ilo[j] = (short)((quad * 8 + j == l15)      ? 0x3F80 : 0);
        ihi[j] = (short)((quad * 8 + j == l15 + 16) ? 0x3F80 : 0);
    }
    int wbase = (w >> 1) * 512 + ((w * 2 + (quad >> 1)) & 3) * 128 + l15 * 8 + (quad & 1) * 4;

    short8 qkfr[8];
    #pragma unroll
    for (int ds = 0; ds < 8; ds++)
        qkfr[ds] = *(const short8*)(qkf + ((size_t)(b * 8 + ds) * 512 + lane * 8));
    float4 qo = *(const float4*)(qkb + b * 16 + quad * 4);

    f32x4 pacc[4];
    #pragma unroll
    for (int u = 0; u < 4; u++) pacc[u] = f32x4{0.f, 0.f, 0.f, 0.f};
    float dp0 = 0.f, dp1 = 0.f, dp2 = 0.f, dp3 = 0.f;

    int tile0 = b * 256 + chunk * 16;

    short8 pf[8];
    #pragma unroll
    for (int i = 0; i < 8; i++)
        pf[i] = *(const short8*)(xgs + (((size_t)(tile0 + w) * 8 + i) * 64 + lane) * 8);

    #pragma unroll 1
    for (int sub = 0; sub < 4; sub++) {
        __syncthreads();
        f32x4 dc = f32x4{0.f, 0.f, 0.f, 0.f};
        #pragma unroll
        for (int ds = 0; ds < 8; ds++)
            dc = __builtin_amdgcn_mfma_f32_16x16x32_bf16(qkfr[ds], pf[ds], dc, 0, 0, 0);
        dc[0] += qo.x; dc[1] += qo.y; dc[2] += qo.z; dc[3] += qo.w;
        float mx = fmaxf(fmaxf(dc[0], dc[1]), fmaxf(dc[2], dc[3]));
        mx = fmaxf(mx, __shfl_xor(mx, 16));
        mx = fmaxf(mx, __shfl_xor(mx, 32));
        float e0 = __expf(dc[0] - mx), e1 = __expf(dc[1] - mx);
        float e2 = __expf(dc[2] - mx), e3 = __expf(dc[3] - mx);
        float lsum = e0 + e1 + e2 + e3;
        lsum += __shfl_xor(lsum, 16); lsum += __shfl_xor(lsum, 32);
        float inv = 1.f / lsum;
        float p0 = e0 * inv, p1 = e1 * inv, p2 = e2 * inv, p3 = e3 * inv;
        dp0 += p0; dp1 += p1; dp2 += p2; dp3 += p3;
        attn[(quad * 4 + 0) * 72 + w * 16 + l15] = f2bf(p0);
        attn[(quad * 4 + 1) * 72 + w * 16 + l15] = f2bf(p1);
        attn[(quad * 4 + 2) * 72 + w * 16 + l15] = f2bf(p2);
        attn[(quad * 4 + 3) * 72 + w * 16 + l15] = f2bf(p3);
        f32x4 zz = f32x4{0.f, 0.f, 0.f, 0.f};
        #pragma unroll
        for (int ds = 0; ds < 8; ds++) {
            f32x4 tlo = __builtin_amdgcn_mfma_f32_16x16x32_bf16(pf[ds], ilo, zz, 0, 0, 0);
            f32x4 thi = __builtin_amdgcn_mfma_f32_16x16x32_bf16(pf[ds], ihi, zz, 0, 0, 0);
            unsigned lo0 = (__float_as_uint(tlo[0]) >> 16) | (__float_as_uint(tlo[1]) & 0xFFFF0000u);
            unsigned lo1 = (__float_as_uint(tlo[2]) >> 16) | (__float_as_uint(tlo[3]) & 0xFFFF0000u);
            unsigned hi0 = (__float_as_uint(thi[0]) >> 16) | (__float_as_uint(thi[1]) & 0xFFFF0000u);
            unsigned hi1 = (__float_as_uint(thi[2]) >> 16) | (__float_as_uint(thi[3]) & 0xFFFF0000u);
            *(uint2*)(&xtT[(ds * 2 + 0) * 1024 + wbase]) = make_uint2(lo0, lo1);
            *(uint2*)(&xtT[(ds * 2 + 1) * 1024 + wbase]) = make_uint2(hi0, hi1);
        }
        if (sub < 3) {
            #pragma unroll
            for (int i = 0; i < 8; i++)
                pf[i] = *(const short8*)(xgs + (((size_t)(tile0 + (sub + 1) * 4 + w) * 8 + i) * 64 + lane) * 8);
        }
        __syncthreads();

        #pragma unroll
        for (int ns = 0; ns < 2; ns++) {
            short8 aa = *(const short8*)(&attn[l15 * 72 + ns * 32 + quad * 8]);
            #pragma unroll
            for (int u = 0; u < 4; u++) {
                short8 bb = *(const short8*)(&xtT[((w * 4 + u) * 2 + ns) * 512 + lane * 8]);
                pacc[u] = __builtin_amdgcn_mfma_f32_16x16x32_bf16(aa, bb, pacc[u], 0, 0, 0);
            }
        }
    }

    #pragma unroll
    for (int m = 1; m < 16; m <<= 1) {
        dp0 += __shfl_xor(dp0, m); dp1 += __shfl_xor(dp1, m);
        dp2 += __shfl_xor(dp2, m); dp3 += __shfl_xor(dp3, m);
    }
    if (l15 == 0) {
        atomicAdd(&denom[b * 16 + quad * 4 + 0], dp0);
        atomicAdd(&denom[b * 16 + quad * 4 + 1], dp1);
        atomicAdd(&denom[b * 16 + quad * 4 + 2], dp2);
        atomicAdd(&denom[b * 16 + quad * 4 + 3], dp3);
    }

    ushort* pout = partials + (size_t)(b * 16 + chunk) * 4096;   // [s][d] bf16
    #pragma unroll
    for (int u = 0; u < 4; u++)
        #pragma unroll
        for (int r = 0; r < 4; r++)
            pout[(quad * 4 + r) * 256 + (w * 4 + u) * 16 + l15] = f2bf(pacc[u][r]);
}

// ---------------- fused tail, 1024 threads; partials read as bf16 --------------------
__global__ void ktail(const ushort* __restrict__ partials, const float* __restrict__ denom,
                      const ushort* __restrict__ vWc, const float* __restrict__ vb,
                      const float* __restrict__ ln2w, const float* __restrict__ ln2b,
                      const ushort* __restrict__ m1Wc, const float* __restrict__ m1b,
                      const ushort* __restrict__ m2Wc, const float* __restrict__ m2b,
                      float* __restrict__ final_out, int write_final,
                      const float* __restrict__ ln1w, const float* __restrict__ ln1b,
                      const ushort* __restrict__ qWc_n, const float* __restrict__ qb_n,
                      const ushort* __restrict__ kWT_n, const float* __restrict__ kb_n,
                      ushort* __restrict__ qkf, float* __restrict__ qkb,
                      float* __restrict__ denom_out, int gen) {
    int b = blockIdx.x, t = threadIdx.x;
    int lane = t & 63, w = t >> 6, l15 = lane & 15, quad = lane >> 4;

    __shared__ char pool[60416];
    __shared__ float dnb[16];
    __shared__ float wr1[16], wr2[16];
    ushort* axsb = (ushort*)pool;                  // [0,8448)
    ushort* s2b  = (ushort*)(pool + 8448);         // [8448,16896)
    float*  slt  = (float*)(pool + 16896);         // [16896,33280)
    ushort* hlb  = (ushort*)(pool + 35328);        // [35328,51968)
    float*  slt2 = (float*)pool;                   // P6 [0,16384)
    ushort* slbq = (ushort*)(pool + 16896);        // P6
    ushort* qkl  = (ushort*)(pool + 16896);        // P6 (after slbq A-frags loaded)
    float*  qsf  = (float*)(pool + 35328);         // P6
    ushort* qsb  = (ushort*)(pool + 51968);        // P6

    // ---- P1: reduce partials chunks (bf16) -> axsb ----
    const ushort* pp = partials + (size_t)b * 65536;
    #pragma unroll
    for (int i = 0; i < 4; i++) {
        int idx = i * 1024 + t;
        float ss = 0.f;
        #pragma unroll
        for (int c = 0; c < 16; c++) ss += bf2f(pp[c * 4096 + idx]);
        axsb[(idx >> 8) * 264 + (idx & 255)] = f2bf(ss);
    }
    if (t < 16) dnb[t] = denom[b * 16 + t];
    __syncthreads();

    // ---- P2: v-apply (MFMA); wave w -> e-tile w ----
    float myv[4];
    {
        short8 af[8];
        #pragma unroll
        for (int ds = 0; ds < 8; ds++)
            af[ds] = *(const short8*)(&axsb[l15 * 264 + ds * 32 + quad * 8]);
        int et = w;
        f32x4 c = f32x4{0.f, 0.f, 0.f, 0.f};
        #pragma unroll
        for (int ds = 0; ds < 8; ds++) {
            short8 bf_ = *(const short8*)(vWc + (size_t)(et * 16 + l15) * 256 + ds * 32 + quad * 8);
            c = __builtin_amdgcn_mfma_f32_16x16x32_bf16(af[ds], bf_, c, 0, 0, 0);
        }
        float vbe = vb[et * 16 + l15];
        #pragma unroll
        for (int r = 0; r < 4; r++) {
            float A = dnb[quad * 4 + r];
            float val = (c[r] + vbe * A) / (A + 1e-7f);
            slt[(quad * 4 + r) * 256 + et * 16 + l15] = val;
            myv[r] = val;
        }
    }
    {
        float s = myv[0] + myv[1] + myv[2] + myv[3];
        float sq = myv[0]*myv[0] + myv[1]*myv[1] + myv[2]*myv[2] + myv[3]*myv[3];
        #pragma unroll
        for (int m = 1; m < 64; m <<= 1) { s += __shfl_xor(s, m); sq += __shfl_xor(sq, m); }
        if (lane == 0) { wr1[w] = s; wr2[w] = sq; }
        __syncthreads();
    }
    float ts = 0.f, tsq = 0.f;
    #pragma unroll
    for (int i = 0; i < 16; i++) { ts += wr1[i]; tsq += wr2[i]; }
    float m2_ = ts * (1.f / 4096.f);
    float rs2 = rsqrtf(tsq * (1.f / 4096.f) - m2_ * m2_ + LN_EPS);
    {
        int e = w * 16 + l15;
        #pragma unroll
        for (int r = 0; r < 4; r++) {
            int ss_ = quad * 4 + r;
            s2b[ss_ * 264 + e] = f2bf((myv[r] - m2_) * rs2 * ln2w[ss_ * 256 + e] + ln2b[ss_ * 256 + e]);
        }
    }
    __syncthreads();

    // ---- P4: MLP1 (MFMA); wave w -> j-tiles {w, w+16} ----
    {
        short8 a2[8];
        #pragma unroll
        for (int ds = 0; ds < 8; ds++)
            a2[ds] = *(const short8*)(&s2b[l15 * 264 + ds * 32 + quad * 8]);
        #pragma unroll
        for (int p = 0; p < 2; p++) {
            int jt = w + p * 16;
            f32x4 c = f32x4{0.f, 0.f, 0.f, 0.f};
            #pragma unroll
            for (int ds = 0; ds < 8; ds++) {
                short8 bf_ = *(const short8*)(m1Wc + (size_t)(jt * 16 + l15) * 256 + ds * 32 + quad * 8);
                c = __builtin_amdgcn_mfma_f32_16x16x32_bf16(a2[ds], bf_, c, 0, 0, 0);
            }
            float bias = m1b[jt * 16 + l15];
            #pragma unroll
            for (int r = 0; r < 4; r++)
                hlb[(quad * 4 + r) * 520 + jt * 16 + l15] = f2bf(fmaxf(c[r] + bias, 0.f));
        }
    }
    __syncthreads();

    // ---- P5: MLP2 (MFMA) + residual; wave w -> d-tile w ----
    {
        short8 a3[16];
        #pragma unroll
        for (int js = 0; js < 16; js++)
            a3[js] = *(const short8*)(&hlb[l15 * 520 + js * 32 + quad * 8]);
        int dt = w;
        f32x4 c = f32x4{0.f, 0.f, 0.f, 0.f};
        #pragma unroll
        for (int js = 0; js < 16; js++) {
            short8 bf_ = *(const short8*)(m2Wc + (size_t)(dt * 16 + l15) * 512 + js * 32 + quad * 8);
            c = __builtin_amdgcn_mfma_f32_16x16x32_bf16(a3[js], bf_, c, 0, 0, 0);
        }
        float b2 = m2b[dt * 16 + l15];
        #pragma unroll
        for (int r = 0; r < 4; r++) {
            int ss_ = quad * 4 + r, d = dt * 16 + l15;
            float val = slt[ss_ * 256 + d] + c[r] + b2;
            slt2[ss_ * 256 + d] = val;
            if (write_final) final_out[(size_t)b * 4096 + ss_ * 256 + d] = val;
        }
    }
    __syncthreads();

    // ---- P6: next-iter q-gen (slots from LDS) ----
    if (gen) {
        int g = t >> 8, cc = t & 255;
        float vals[4]; float s = 0.f, sq = 0.f;
        #pragma unroll
        for (int kk = 0; kk < 4; kk++) {
            float v = slt2[(g * 4 + kk) * 256 + cc];
            vals[kk] = v; s += v; sq += v * v;
        }
        #pragma unroll
        for (int m = 1; m < 64; m <<= 1) { s += __shfl_xor(s, m); sq += __shfl_xor(sq, m); }
        if (lane == 0) { wr1[w] = s; wr2[w] = sq; }
        __syncthreads();
        float ts1 = 0.f, tsq1 = 0.f;
        #pragma unroll
        for (int i = 0; i < 16; i++) { ts1 += wr1[i]; tsq1 += wr2[i]; }
        float m1_ = ts1 * (1.f / 4096.f);
        float rs1 = rsqrtf(tsq1 * (1.f / 4096.f) - m1_ * m1_ + LN_EPS);
        #pragma unroll
        for (int kk = 0; kk < 4; kk++) {
            int k = g * 4 + kk;
            slbq[k * 264 + cc] = f2bf((vals[kk] - m1_) * rs1 * ln1w[k * 256 + cc] + ln1b[k * 256 + cc]);
        }
        __syncthreads();
        qgen_core(b, t, lane, w, l15, quad, slbq, qsf, qsb, qkl,
                  qWc_n, qb_n, kWT_n, kb_n, qkf, qkb, denom_out);
    }
}

extern "C" void kernel_launch(void* const* d_in, const int* in_sizes, int n_in,
                              void* d_out, int out_size, void* d_ws, size_t ws_size,
                              hipStream_t stream) {
    const float* inputs     = (const float*)d_in[0];
    const float* slots_init = (const float*)d_in[1];
    const float* mu         = (const float*)d_in[2];
    const float* logsig     = (const float*)d_in[3];
    const float* ln0w       = (const float*)d_in[4];
    const float* ln0b       = (const float*)d_in[5];
    const float* ln1w       = (const float*)d_in[6];
    const float* ln1b       = (const float*)d_in[7];
    const float* ln2w       = (const float*)d_in[8];
    const float* ln2b       = (const float*)d_in[9];
    const float* qW         = (const float*)d_in[10];
    const float* qb         = (const float*)d_in[11];
    const float* kW         = (const float*)d_in[12];
    const float* kb         = (const float*)d_in[13];
    const float* vW         = (const float*)d_in[14];
    const float* vb         = (const float*)d_in[15];
    const float* m1W        = (const float*)d_in[16];
    const float* m1b        = (const float*)d_in[17];
    const float* m2W        = (const float*)d_in[18];
    const float* m2b        = (const float*)d_in[19];

    char* ws = (char*)d_ws;
    ushort* xgs     = (ushort*)(ws);                   // 134,217,728 B
    ushort* partials= (ushort*)(ws + 134217728);       //   8,388,608 B (bf16)
    ushort* qkf     = (ushort*)(ws + 150994944);       //     524,288 B
    ushort* qWc     = (ushort*)(ws + 153616384);       //     393,216 B
    ushort* m1Wc    = (ushort*)(ws + 154009600);       //     786,432 B
    ushort* m2Wc    = (ushort*)(ws + 154796032);       //     786,432 B
    ushort* vWc     = (ushort*)(ws + 155582464);       //     393,216 B
    float*  denom   = (float*)(ws + 155975680);        //       4,096 B
    float*  qkb     = (float*)(ws + 155979776);        //       4,096 B
    float*  sums    = (float*)(ws + 155983872);        //         512 B
    ushort* kWT     = (ushort*)(ws + 155984384);       //     393,216 B
    // total 156,377,600 B <= 157,295,104 B proven available

    hipMemsetAsync(sums, 0, 512, stream);
    kprep<<<2384, 256, 0, stream>>>(qW, kW, m1W, m2W, vW, qWc, kWT, m1Wc, m2Wc, vWc,
                                    inputs, sums);
    lkq<<<320, 1024, 0, stream>>>(inputs, ln0w, ln0b, sums, xgs,
                                  slots_init, mu, logsig, ln1w, ln1b,
                                  qWc, qb, kWT, kb, qkf, qkb, denom);

    for (int it = 0; it < 3; it++) {
        katt<<<1024, 256, 0, stream>>>(xgs, qkf, qkb, denom, partials);
        int nx = (it < 2) ? it + 1 : 2;
        ktail<<<64, 1024, 0, stream>>>(partials, denom,
                                       vWc + it * 65536, vb + it * 256, ln2w, ln2b,
                                       m1Wc + it * 131072, m1b + it * 512,
                                       m2Wc + it * 131072, m2b + it * 256,
                                       (float*)d_out, it == 2 ? 1 : 0,
                                       ln1w, ln1b,
                                       qWc + nx * 65536, qb + nx * 256,
                                       kWT + nx * 65536, kb + nx * 256,
                                       qkf, qkb, denom, it < 2 ? 1 : 0);
    }
}